// Round 1
// baseline (556.510 us; speedup 1.0000x reference)
//
#include <hip/hip_runtime.h>

// ---- problem constants ----
#define V_DIM   2048
#define Q_DIM   1024
#define NUM_HID 1024
#define BB 64
#define KK 12
#define NN 36
#define M_ROWS (BB*KK*NN)    // 27648 = 216 * 128, exact
#define BKROWS (BB*KK)       // 768   = 6 * 128,   exact

typedef unsigned short u16;
typedef __bf16 bf16x8  __attribute__((ext_vector_type(8)));
typedef u16    ushort8 __attribute__((ext_vector_type(8)));
typedef float  floatx4 __attribute__((ext_vector_type(4)));

// fp32 -> bf16, round-to-nearest-even (inputs are finite gaussians; no NaN path)
__device__ __forceinline__ u16 f2bf(float f) {
    unsigned u = __float_as_uint(f);
    u += 0x7fffu + ((u >> 16) & 1u);
    return (u16)(u >> 16);
}

// async global->LDS, 16B per lane. LDS dest = wave-uniform base + lane*16 (HW).
__device__ __forceinline__ void gload16(const u16* g, u16* l) {
    __builtin_amdgcn_global_load_lds((const __attribute__((address_space(1))) void*)g,
                                     (__attribute__((address_space(3))) void*)l, 16, 0, 0);
}

// ---- ||W1||^2 reduction (1024x3072 fp32) -> atomicAdd into wsf[0] ----
__global__ void norm_w1_kernel(const float* __restrict__ W1, float* __restrict__ acc)
{
    float s = 0.f;
    const float4* p = (const float4*)W1;
    const int total = (NUM_HID * (V_DIM + Q_DIM)) / 4;   // 786432
    for (int i = blockIdx.x * 256 + threadIdx.x; i < total; i += 256 * 256) {
        float4 f = p[i];
        s += f.x * f.x + f.y * f.y + f.z * f.z + f.w * f.w;
    }
    #pragma unroll
    for (int off = 32; off > 0; off >>= 1) s += __shfl_down(s, off);
    __shared__ float red[4];
    if ((threadIdx.x & 63) == 0) red[threadIdx.x >> 6] = s;
    __syncthreads();
    if (threadIdx.x == 0) atomicAdd(acc, red[0] + red[1] + red[2] + red[3]);
}

// ---- ||W2||^2 (1024) + final scales: wsf[2]=g1/||W1||, wsf[3]=g2/||W2|| ----
__global__ void scale_kernel(const float* __restrict__ W2, const float* __restrict__ g1,
                             const float* __restrict__ g2, float* __restrict__ wsf)
{
    float v = W2[threadIdx.x];          // blockDim = 1024
    float s = v * v;
    #pragma unroll
    for (int off = 32; off > 0; off >>= 1) s += __shfl_down(s, off);
    __shared__ float red[16];
    if ((threadIdx.x & 63) == 0) red[threadIdx.x >> 6] = s;
    __syncthreads();
    if (threadIdx.x == 0) {
        float t = 0.f;
        #pragma unroll
        for (int u = 0; u < 16; u++) t += red[u];
        wsf[2] = g1[0] / sqrtf(wsf[0]);
        wsf[3] = g2[0] / sqrtf(t);
    }
}

// ---- W1 fp32 (1024 x 3072, row-major) -> bf16 W1v (1024x2048) + W1q (1024x1024) ----
__global__ void convert_w1_kernel(const float* __restrict__ W1,
                                  u16* __restrict__ W1v, u16* __restrict__ W1q)
{
    int s = blockIdx.x * 256 + threadIdx.x;          // grid 1536*256 = 393216 exact
    if (s >= NUM_HID * (V_DIM + Q_DIM) / 8) return;
    int h = s / 384, g = s % 384;
    const float4* p = (const float4*)(W1 + (size_t)h * (V_DIM + Q_DIM) + g * 8);
    float4 a = p[0], b = p[1];
    ushort8 o;
    o[0]=f2bf(a.x); o[1]=f2bf(a.y); o[2]=f2bf(a.z); o[3]=f2bf(a.w);
    o[4]=f2bf(b.x); o[5]=f2bf(b.y); o[6]=f2bf(b.z); o[7]=f2bf(b.w);
    if (g < 256) *(ushort8*)(W1v + (size_t)h * V_DIM + g * 8) = o;
    else         *(ushort8*)(W1q + (size_t)h * Q_DIM + (g - 256) * 8) = o;
}

// ---- v fp32 [27648][2048] -> bf16 same layout (one streaming pass) ----
__global__ void convert_v_kernel(const float* __restrict__ v, u16* __restrict__ vbf)
{
    const int total = (M_ROWS * V_DIM) / 8;          // 7,077,888 8-elem groups
    for (int s = blockIdx.x * 256 + threadIdx.x; s < total; s += 2048 * 256) {
        const float4* p = (const float4*)(v + (size_t)s * 8);
        float4 a = p[0], b = p[1];
        ushort8 o;
        o[0]=f2bf(a.x); o[1]=f2bf(a.y); o[2]=f2bf(a.z); o[3]=f2bf(a.w);
        o[4]=f2bf(b.x); o[5]=f2bf(b.y); o[6]=f2bf(b.z); o[7]=f2bf(b.w);
        *(ushort8*)(vbf + (size_t)s * 8) = o;
    }
}

// ---- MFMA GEMM: C(M x 1024) = A(M x GK) * B(GK x 1024)
//      B passed as bf16 [1024][GK] row-major (n-major, k contiguous) = W1 slice.
// ABF16=true : A is pre-converted bf16, staged via global_load_lds w/ XOR swizzle
// ABF16=false: A is fp32, converted on the fly (reg-staged, padded LDS)
// MAIN=true  : fused epilogue  partial[row][tx*2+wn] = sum_cols relu(s1*(acc+hq)+b1)*W2
// MAIN=false : writes raw acc to outp[row*1024 + col]   (the hq pass)
// Tiles: BM=BN=128, BK=64. 256 threads = 4 waves (2x2), each wave 64x64 via 4x4 MFMA tiles.
// Swizzled LDS (rule 21): linear dest for global_load_lds; source group pre-swizzled
// g_src = g ^ (row&7); reads apply the same involution -> 2-way bank aliasing (free).
// XCD swizzle (m204 bijective, nwg%8==0): the 8 n-tiles sharing an A panel land on
// one XCD -> A panel (512KB) + whole B (4MB) are L2-resident.
template<int GK, bool MAIN, bool ABF16>
__global__ __launch_bounds__(256, 2)
void gemm_kernel(const void* __restrict__ Asrc,
                 const u16*  __restrict__ Bsrc,
                 float*      __restrict__ outp,
                 const float* __restrict__ hq,
                 const float* __restrict__ b1,
                 const float* __restrict__ W2,
                 const float* __restrict__ scl)
{
    __shared__ u16 As[ABF16 ? 128 * 64 : 128 * 72];
    __shared__ u16 Bs[128 * 64];

    const int tid  = threadIdx.x;
    const int lane = tid & 63;
    const int wv   = tid >> 6;
    const int wm   = wv & 1;          // wave row (0..1)
    const int wn   = wv >> 1;         // wave col (0..1)
    const int quad = lane >> 4;
    const int l15  = lane & 15;

    // bijective XCD swizzle; both grids have gridDim.x == 8 and nwg % 8 == 0
    const int bid  = blockIdx.y * 8 + blockIdx.x;
    const int nwg  = gridDim.x * gridDim.y;
    const int tile = (bid & 7) * (nwg >> 3) + (bid >> 3);
    const int tx   = tile & 7;
    const int ty   = tile >> 3;
    const int m0   = ty * 128;
    const int n0   = tx * 128;

    floatx4 acc[4][4];
    #pragma unroll
    for (int i = 0; i < 4; i++)
        #pragma unroll
        for (int j = 0; j < 4; j++)
            acc[i][j] = (floatx4){0.f, 0.f, 0.f, 0.f};

    for (int kt = 0; kt < GK / 64; ++kt) {
        const int k0 = kt * 64;
        __syncthreads();
        // ---- stage A ----
        if constexpr (ABF16) {
            const u16* Ab = (const u16*)Asrc;
            #pragma unroll
            for (int it = 0; it < 4; ++it) {
                int sbase = it * 256 + wv * 64;            // wave-uniform slot base
                int s = sbase + lane;
                int r = s >> 3, g = s & 7;
                int gs = g ^ (r & 7);                      // pre-swizzled source group
                gload16(Ab + (size_t)(m0 + r) * GK + k0 + gs * 8, &As[sbase * 8]);
            }
        } else {
            const float* Af = (const float*)Asrc;
            #pragma unroll
            for (int it = 0; it < 4; ++it) {
                int s = tid + 256 * it;
                int r = s >> 3, g = s & 7;
                const float4* gp = (const float4*)(Af + (size_t)(m0 + r) * GK + k0 + g * 8);
                float4 f0 = gp[0];
                float4 f1 = gp[1];
                ushort8 o;
                o[0]=f2bf(f0.x); o[1]=f2bf(f0.y); o[2]=f2bf(f0.z); o[3]=f2bf(f0.w);
                o[4]=f2bf(f1.x); o[5]=f2bf(f1.y); o[6]=f2bf(f1.z); o[7]=f2bf(f1.w);
                *(ushort8*)(&As[r * 72 + g * 8]) = o;
            }
        }
        // ---- stage B (always bf16, global_load_lds, swizzled source) ----
        #pragma unroll
        for (int it = 0; it < 4; ++it) {
            int sbase = it * 256 + wv * 64;
            int s = sbase + lane;
            int c = s >> 3, g = s & 7;
            int gs = g ^ (c & 7);
            gload16(Bsrc + (size_t)(n0 + c) * GK + k0 + gs * 8, &Bs[sbase * 8]);
        }
        __syncthreads();
        // ---- compute: 2 k-steps of 32 ----
        #pragma unroll
        for (int ks = 0; ks < 2; ++ks) {
            bf16x8 af[4], bfr[4];
            #pragma unroll
            for (int i = 0; i < 4; i++) {
                int rA = wm * 64 + i * 16 + l15;
                if constexpr (ABF16) {
                    int off = (ks * 32 + quad * 8) ^ ((rA & 7) << 3);
                    af[i] = *(const bf16x8*)(&As[rA * 64 + off]);
                } else {
                    af[i] = *(const bf16x8*)(&As[rA * 72 + ks * 32 + quad * 8]);
                }
            }
            #pragma unroll
            for (int j = 0; j < 4; j++) {
                int c = wn * 64 + j * 16 + l15;
                int off = (ks * 32 + quad * 8) ^ ((c & 7) << 3);
                bfr[j] = *(const bf16x8*)(&Bs[c * 64 + off]);
            }
            #pragma unroll
            for (int i = 0; i < 4; i++)
                #pragma unroll
                for (int j = 0; j < 4; j++)
                    acc[i][j] = __builtin_amdgcn_mfma_f32_16x16x32_bf16(af[i], bfr[j], acc[i][j], 0, 0, 0);
        }
    }

    if constexpr (MAIN) {
        const float s1 = scl[2];
        int   cg[4];
        float w2v[4], b1v[4];
        #pragma unroll
        for (int j = 0; j < 4; j++) {
            cg[j]  = n0 + wn * 64 + j * 16 + l15;
            w2v[j] = W2[cg[j]];
            b1v[j] = b1[cg[j]];
        }
        #pragma unroll
        for (int i = 0; i < 4; i++) {
            #pragma unroll
            for (int r = 0; r < 4; r++) {
                const int mg = m0 + wm * 64 + i * 16 + quad * 4 + r;
                const int bk = mg / NN;
                float p = 0.f;
                #pragma unroll
                for (int j = 0; j < 4; j++) {
                    float pre = s1 * (acc[i][j][r] + hq[(size_t)bk * NUM_HID + cg[j]]) + b1v[j];
                    p += fmaxf(pre, 0.f) * w2v[j];
                }
                // reduce over the 16 column-lanes of this quad (row is quad-local)
                p += __shfl_xor(p, 1);
                p += __shfl_xor(p, 2);
                p += __shfl_xor(p, 4);
                p += __shfl_xor(p, 8);
                if (l15 == 0)
                    outp[(size_t)mg * 16 + tx * 2 + wn] = p;
            }
        }
    } else {
        #pragma unroll
        for (int i = 0; i < 4; i++)
            #pragma unroll
            for (int r = 0; r < 4; r++) {
                const int mg = m0 + wm * 64 + i * 16 + quad * 4 + r;
                #pragma unroll
                for (int j = 0; j < 4; j++) {
                    const int c = n0 + wn * 64 + j * 16 + l15;
                    outp[(size_t)mg * NUM_HID + c] = acc[i][j][r];
                }
            }
    }
}

// ---- softmax over K=12 per (b,n); logits = s2*sum(partials) + b2 ----
__global__ void softmax_kernel(const float* __restrict__ part,
                               const float* __restrict__ scl,
                               const float* __restrict__ b2,
                               float* __restrict__ out)
{
    int t = blockIdx.x * 256 + threadIdx.x;   // grid 9*256 = 2304 exact
    if (t >= BB * NN) return;
    int b = t / NN, n = t % NN;
    float s2 = scl[3], bias = b2[0];
    float lg[KK];
    float mx = -1e30f;
    #pragma unroll
    for (int k = 0; k < KK; k++) {
        int m = (b * KK + k) * NN + n;
        const float4* pp = (const float4*)(part + (size_t)m * 16);
        float4 a0 = pp[0], a1 = pp[1], a2 = pp[2], a3 = pp[3];
        float s = (a0.x + a0.y + a0.z + a0.w) + (a1.x + a1.y + a1.z + a1.w)
                + (a2.x + a2.y + a2.z + a2.w) + (a3.x + a3.y + a3.z + a3.w);
        lg[k] = s2 * s + bias;
        mx = fmaxf(mx, lg[k]);
    }
    float den = 0.f;
    #pragma unroll
    for (int k = 0; k < KK; k++) { lg[k] = expf(lg[k] - mx); den += lg[k]; }
    float inv = 1.0f / den;
    #pragma unroll
    for (int k = 0; k < KK; k++) out[(size_t)((b * KK + k) * NN + n)] = lg[k] * inv;
}

extern "C" void kernel_launch(void* const* d_in, const int* in_sizes, int n_in,
                              void* d_out, int out_size, void* d_ws, size_t ws_size,
                              hipStream_t stream)
{
    (void)in_sizes; (void)n_in; (void)out_size;
    const float* v  = (const float*)d_in[0];
    const float* q  = (const float*)d_in[1];
    const float* W1 = (const float*)d_in[2];
    const float* g1 = (const float*)d_in[3];
    const float* b1 = (const float*)d_in[4];
    const float* W2 = (const float*)d_in[5];
    const float* g2 = (const float*)d_in[6];
    const float* b2 = (const float*)d_in[7];
    float* out = (float*)d_out;

    // ws layout (bytes):
    //   0        : 4 floats  [w1_sumsq, unused, s1, s2]
    //   16       : hq  fp32 [768][1024]          (3,145,728 B)
    //   3145744  : W1v bf16 [1024][2048]         (4,194,304 B)
    //   7340048  : W1q bf16 [1024][1024]         (2,097,152 B)
    //   9437200  : part fp32 [27648][16]         (1,769,472 B)
    //   11206672 : vbf bf16 [27648][2048]        (113,246,208 B) -> total ~124.5 MB
    char*  ws   = (char*)d_ws;
    float* wsf  = (float*)ws;
    float* hq   = (float*)(ws + 16);
    u16*   W1v  = (u16*)  (ws + 16 + 3145728);
    u16*   W1q  = (u16*)  (ws + 16 + 3145728 + 4194304);
    float* part = (float*)(ws + 16 + 3145728 + 4194304 + 2097152);
    u16*   vbf  = (u16*)  (ws + 16 + 3145728 + 4194304 + 2097152 + 1769472);
    const size_t ws_need = 16ull + 3145728 + 4194304 + 2097152 + 1769472
                         + (size_t)M_ROWS * V_DIM * 2;   // 124,452,880
    const bool pre = (ws_size >= ws_need);

    hipMemsetAsync(d_ws, 0, 16, stream);
    norm_w1_kernel<<<256, 256, 0, stream>>>(W1, wsf);
    scale_kernel<<<1, 1024, 0, stream>>>(W2, g1, g2, wsf);
    convert_w1_kernel<<<1536, 256, 0, stream>>>(W1, W1v, W1q);
    // hq = q @ W1q^T (raw, unscaled):  M=768 -> grid (8 ntiles, 6 mtiles)
    gemm_kernel<Q_DIM, false, false><<<dim3(8, 6), 256, 0, stream>>>(
        q, W1q, hq, nullptr, nullptr, nullptr, wsf);
    if (pre) {
        // one-time fp32->bf16 of v, then pure-bf16 main GEMM via global_load_lds
        convert_v_kernel<<<2048, 256, 0, stream>>>(v, vbf);
        gemm_kernel<V_DIM, true, true><<<dim3(8, 216), 256, 0, stream>>>(
            vbf, W1v, part, hq, b1, W2, wsf);
    } else {
        // fallback: on-the-fly conversion (previous behavior, + gld_lds B staging)
        gemm_kernel<V_DIM, true, false><<<dim3(8, 216), 256, 0, stream>>>(
            v, W1v, part, hq, b1, W2, wsf);
    }
    softmax_kernel<<<9, 256, 0, stream>>>(part, wsf, b2, out);
}